// Round 3
// baseline (84.061 us; speedup 1.0000x reference)
//
#include <hip/hip_runtime.h>
#include <hip/hip_bf16.h>

typedef __attribute__((ext_vector_type(8))) short bf16x8;
typedef __attribute__((ext_vector_type(4))) float f32x4;

__device__ __forceinline__ unsigned short f2bf(float f) {
    union { float f; unsigned int u; } v; v.f = f;
    unsigned int u = v.u;
    unsigned int r = u + 0x7FFFu + ((u >> 16) & 1u);   // RNE
    return (unsigned short)(r >> 16);
}

// ---------------- kernel 0: W transpose+convert -> Wt[192][384] bf16 ----------------
__global__ __launch_bounds__(256) void wprep(const float* __restrict__ Wq,
                                             const float* __restrict__ Wk,
                                             const float* __restrict__ Wv,
                                             unsigned short* __restrict__ Wt) {
    int idx = blockIdx.x * 256 + threadIdx.x;          // 3*64*384 = 73728
    if (idx >= 3 * 64 * 384) return;
    int w   = idx / (64 * 384);
    int rem = idx % (64 * 384);
    int n = rem / 384, k = rem % 384;
    const float* W = (w == 0) ? Wq : ((w == 1) ? Wk : Wv);
    Wt[idx] = f2bf(W[k * 64 + n]);
}

// ---------------- kernel 1: qkv = x @ [Wq|Wk|Wv], bf16 MFMA, NO LDS, NO BARRIERS ----
// M=65536, K=384, N=192. 8 waves/block, wave tile 64x96 (wr=wid>>1, wc=wid&1).
// A-rows are wave-exclusive (2x reuse within block -> L1/L2 dedup), B (Wt) is
// L2-hot, so all fragments load DIRECTLY from global:
//   A: per-lane fp32 rows, converted to bf16 in-register.
//   B: pre-transposed Wt -> contiguous 16B bf16x8 fragment loads.
// 12 sub-steps of K=32, 1-deep register pipeline (even/odd buffers, fully
// unrolled so all indices are static). No __syncthreads anywhere -> waves
// drift and keep the HBM pipe continuously fed.
__global__ __launch_bounds__(512) void qkv_gemm(const float* __restrict__ x,
                                                const unsigned short* __restrict__ Wt,
                                                unsigned short* __restrict__ q_ws,
                                                unsigned short* __restrict__ k_ws,
                                                unsigned short* __restrict__ vt_ws) {
    const int tid  = threadIdx.x;
    const int lane = tid & 63;
    const int wid  = tid >> 6;
    const int wr = wid >> 1, wc = wid & 1;       // 4 x 2 wave grid
    const int l15 = lane & 15, lg = lane >> 4;
    const int rowb = blockIdx.x * 256 + wr * 64; // wave's exclusive A-row base
    const float* xw = x + (size_t)(rowb + l15) * 384 + lg * 8;          // frag m: + m*16*384
    const unsigned short* Ww = Wt + (size_t)(wc * 96 + l15) * 384 + lg * 8; // frag n: + n*16*384

    f32x4 acc[4][6] = {};
    float4 aRaw[2][8];   // [buf][m*2+half]
    bf16x8 bRaw[2][6];   // [buf][n]

    // prologue: load sub-step 0
#pragma unroll
    for (int m = 0; m < 4; ++m) {
        aRaw[0][m * 2 + 0] = *reinterpret_cast<const float4*>(xw + (size_t)m * 16 * 384);
        aRaw[0][m * 2 + 1] = *reinterpret_cast<const float4*>(xw + (size_t)m * 16 * 384 + 4);
    }
#pragma unroll
    for (int n = 0; n < 6; ++n)
        bRaw[0][n] = *reinterpret_cast<const bf16x8*>(Ww + (size_t)n * 16 * 384);

#pragma unroll
    for (int ss = 0; ss < 12; ++ss) {
        const int cur = ss & 1, nxt = cur ^ 1;
        // issue next sub-step loads first (independent -> in flight under MFMA)
        if (ss < 11) {
            const int k1 = (ss + 1) * 32;
#pragma unroll
            for (int m = 0; m < 4; ++m) {
                aRaw[nxt][m * 2 + 0] = *reinterpret_cast<const float4*>(xw + (size_t)m * 16 * 384 + k1);
                aRaw[nxt][m * 2 + 1] = *reinterpret_cast<const float4*>(xw + (size_t)m * 16 * 384 + k1 + 4);
            }
#pragma unroll
            for (int n = 0; n < 6; ++n)
                bRaw[nxt][n] = *reinterpret_cast<const bf16x8*>(Ww + (size_t)n * 16 * 384 + k1);
        }
        // convert current A to bf16 fragments
        bf16x8 a[4];
#pragma unroll
        for (int m = 0; m < 4; ++m) {
            const float4& f0 = aRaw[cur][m * 2 + 0];
            const float4& f1 = aRaw[cur][m * 2 + 1];
            a[m][0] = (short)f2bf(f0.x); a[m][1] = (short)f2bf(f0.y);
            a[m][2] = (short)f2bf(f0.z); a[m][3] = (short)f2bf(f0.w);
            a[m][4] = (short)f2bf(f1.x); a[m][5] = (short)f2bf(f1.y);
            a[m][6] = (short)f2bf(f1.z); a[m][7] = (short)f2bf(f1.w);
        }
        // 24 MFMA
#pragma unroll
        for (int m = 0; m < 4; ++m)
#pragma unroll
            for (int n = 0; n < 6; ++n)
                acc[m][n] = __builtin_amdgcn_mfma_f32_16x16x32_bf16(a[m], bRaw[cur][n], acc[m][n], 0, 0, 0);
    }

    // epilogue: C/D layout col=lane&15, row=(lane>>4)*4+j
#pragma unroll
    for (int m = 0; m < 4; ++m) {
#pragma unroll
        for (int n = 0; n < 6; ++n) {
            int colb = wc * 96 + n * 16 + l15;
#pragma unroll
            for (int j = 0; j < 4; ++j) {
                int row = rowb + m * 16 + lg * 4 + j;
                unsigned short hv = f2bf(acc[m][n][j]);
                if (colb < 64) {
                    q_ws[(size_t)row * 64 + colb] = hv;
                } else if (colb < 128) {
                    k_ws[(size_t)row * 64 + (colb - 64)] = hv;
                } else {
                    int bb = row >> 8, t = row & 255, h = colb - 128;
                    vt_ws[((size_t)bb * 64 + h) * 256 + t] = hv;   // v stored transposed
                }
            }
        }
    }
}

// ---------------- kernel 2: causal flash attention, one block per batch ----------------
__global__ __launch_bounds__(256, 1) void attn(const unsigned short* __restrict__ q_ws,
                                               const unsigned short* __restrict__ k_ws,
                                               const unsigned short* __restrict__ vt_ws,
                                               float* __restrict__ out) {
    __shared__ unsigned short P_lds[4][64][72];   // per-wave P staging, padded

    const int b = blockIdx.x;
    const int tid = threadIdx.x, lane = tid & 63, w = tid >> 6;
    const int l15 = lane & 15, lg = lane >> 4;
    const unsigned short* qb = q_ws + (size_t)b * 256 * 64;
    const unsigned short* kb = k_ws + (size_t)b * 256 * 64;
    const unsigned short* vb = vt_ws + (size_t)b * 64 * 256;
    float* ob = out + (size_t)b * 256 * 64;
    const int r0 = w * 64;
    const float scale = 0.05103103630798287f;     // 384^-0.5

    f32x4 o[4][4] = {};
    float M[4][4], L[4][4];
#pragma unroll
    for (int m = 0; m < 4; ++m)
#pragma unroll
        for (int j = 0; j < 4; ++j) { M[m][j] = -1e30f; L[m][j] = 0.f; }

    for (int jt = 0; jt <= w; ++jt) {
        // ---- S = q @ K^T for this 64-col tile ----
        f32x4 s[4][4] = {};
#pragma unroll
        for (int kk = 0; kk < 2; ++kk) {
            bf16x8 aq[4], bk[4];
#pragma unroll
            for (int m = 0; m < 4; ++m)
                aq[m] = *reinterpret_cast<const bf16x8*>(qb + (size_t)(r0 + m * 16 + l15) * 64 + kk * 32 + lg * 8);
#pragma unroll
            for (int n = 0; n < 4; ++n)
                bk[n] = *reinterpret_cast<const bf16x8*>(kb + (size_t)(jt * 64 + n * 16 + l15) * 64 + kk * 32 + lg * 8);
#pragma unroll
            for (int m = 0; m < 4; ++m)
#pragma unroll
                for (int n = 0; n < 4; ++n)
                    s[m][n] = __builtin_amdgcn_mfma_f32_16x16x32_bf16(aq[m], bk[n], s[m][n], 0, 0, 0);
        }
        // ---- scale + causal mask + tile row-max ----
        float tm[4][4];
#pragma unroll
        for (int m = 0; m < 4; ++m)
#pragma unroll
            for (int j = 0; j < 4; ++j) tm[m][j] = -1e30f;
#pragma unroll
        for (int m = 0; m < 4; ++m) {
#pragma unroll
            for (int n = 0; n < 4; ++n) {
                int colg = jt * 64 + n * 16 + l15;
#pragma unroll
                for (int j = 0; j < 4; ++j) {
                    int rowg = r0 + m * 16 + lg * 4 + j;
                    float v = s[m][n][j] * scale;
                    if (colg > rowg) v = -1e30f;
                    s[m][n][j] = v;
                    tm[m][j] = fmaxf(tm[m][j], v);
                }
            }
        }
#pragma unroll
        for (int m = 0; m < 4; ++m)
#pragma unroll
            for (int j = 0; j < 4; ++j) {
                float v = tm[m][j];
                v = fmaxf(v, __shfl_xor(v, 1));
                v = fmaxf(v, __shfl_xor(v, 2));
                v = fmaxf(v, __shfl_xor(v, 4));
                v = fmaxf(v, __shfl_xor(v, 8));
                tm[m][j] = v;
            }
        float alpha[4][4];
#pragma unroll
        for (int m = 0; m < 4; ++m)
#pragma unroll
            for (int j = 0; j < 4; ++j) {
                float mn = fmaxf(M[m][j], tm[m][j]);
                alpha[m][j] = __expf(M[m][j] - mn);
                M[m][j] = mn;
            }
        // ---- P = exp(S - M), tile row-sum ----
        float ts[4][4] = {};
#pragma unroll
        for (int m = 0; m < 4; ++m)
#pragma unroll
            for (int n = 0; n < 4; ++n)
#pragma unroll
                for (int j = 0; j < 4; ++j) {
                    float p = __expf(s[m][n][j] - M[m][j]);
                    s[m][n][j] = p;
                    ts[m][j] += p;
                }
#pragma unroll
        for (int m = 0; m < 4; ++m)
#pragma unroll
            for (int j = 0; j < 4; ++j) {
                float v = ts[m][j];
                v += __shfl_xor(v, 1);
                v += __shfl_xor(v, 2);
                v += __shfl_xor(v, 4);
                v += __shfl_xor(v, 8);
                L[m][j] = L[m][j] * alpha[m][j] + v;
            }
        // ---- rescale O ----
#pragma unroll
        for (int m = 0; m < 4; ++m)
#pragma unroll
            for (int n = 0; n < 4; ++n)
#pragma unroll
                for (int j = 0; j < 4; ++j) o[m][n][j] *= alpha[m][j];
        // ---- P -> LDS (bf16) for A-operand restage ----
#pragma unroll
        for (int m = 0; m < 4; ++m)
#pragma unroll
            for (int n = 0; n < 4; ++n)
#pragma unroll
                for (int j = 0; j < 4; ++j)
                    P_lds[w][m * 16 + lg * 4 + j][n * 16 + l15] = f2bf(s[m][n][j]);
        asm volatile("s_waitcnt lgkmcnt(0)" ::: "memory");   // wave-internal LDS RAW fence
        // ---- O += P @ V  (V transposed in global: vb[h][t]) ----
#pragma unroll
        for (int kk = 0; kk < 2; ++kk) {
            bf16x8 ap[4], bv[4];
#pragma unroll
            for (int m = 0; m < 4; ++m)
                ap[m] = *reinterpret_cast<const bf16x8*>(&P_lds[w][m * 16 + l15][kk * 32 + lg * 8]);
#pragma unroll
            for (int n = 0; n < 4; ++n)
                bv[n] = *reinterpret_cast<const bf16x8*>(vb + (size_t)(n * 16 + l15) * 256 + jt * 64 + kk * 32 + lg * 8);
#pragma unroll
            for (int m = 0; m < 4; ++m)
#pragma unroll
                for (int n = 0; n < 4; ++n)
                    o[m][n] = __builtin_amdgcn_mfma_f32_16x16x32_bf16(ap[m], bv[n], o[m][n], 0, 0, 0);
        }
    }
    // ---- normalize + store fp32 ----
#pragma unroll
    for (int m = 0; m < 4; ++m) {
#pragma unroll
        for (int n = 0; n < 4; ++n) {
            int h = n * 16 + l15;
#pragma unroll
            for (int j = 0; j < 4; ++j) {
                int t = r0 + m * 16 + lg * 4 + j;
                ob[(size_t)t * 64 + h] = o[m][n][j] / L[m][j];
            }
        }
    }
}

extern "C" void kernel_launch(void* const* d_in, const int* in_sizes, int n_in,
                              void* d_out, int out_size, void* d_ws, size_t ws_size,
                              hipStream_t stream) {
    const float* x  = (const float*)d_in[0];
    const float* Wq = (const float*)d_in[1];
    const float* Wk = (const float*)d_in[2];
    const float* Wv = (const float*)d_in[3];
    float* out = (float*)d_out;

    char* ws = (char*)d_ws;
    unsigned short* q_ws  = (unsigned short*)(ws);                 // [65536][64] bf16
    unsigned short* k_ws  = (unsigned short*)(ws + 8388608);       // [65536][64] bf16
    unsigned short* vt_ws = (unsigned short*)(ws + 16777216);      // [256][64][256] bf16 (v^T)
    unsigned short* Wt    = (unsigned short*)(ws + 25165824);      // [192][384] bf16

    wprep<<<288, 256, 0, stream>>>(Wq, Wk, Wv, Wt);
    qkv_gemm<<<256, 512, 0, stream>>>(x, Wt, q_ws, k_ws, vt_ws);
    attn<<<256, 256, 0, stream>>>(q_ws, k_ws, vt_ws, out);
}

// Round 4
// 61.962 us; speedup vs baseline: 1.3567x; 1.3567x over previous
//
#include <hip/hip_runtime.h>
#include <hip/hip_bf16.h>

typedef __attribute__((ext_vector_type(8))) short bf16x8;
typedef __attribute__((ext_vector_type(4))) float f32x4;

__device__ __forceinline__ unsigned short f2bf(float f) {
    union { float f; unsigned int u; } v; v.f = f;
    unsigned int u = v.u;
    unsigned int r = u + 0x7FFFu + ((u >> 16) & 1u);   // RNE
    return (unsigned short)(r >> 16);
}

#define GLDS16(gsrc, ldst)                                                          \
    __builtin_amdgcn_global_load_lds(                                               \
        (const __attribute__((address_space(1))) unsigned int*)(gsrc),              \
        (__attribute__((address_space(3))) unsigned int*)(ldst), 16, 0, 0)

// ---------------- kernel 0: W transpose+convert -> Wt[192][384] bf16 ----------------
__global__ __launch_bounds__(256) void wprep(const float* __restrict__ Wq,
                                             const float* __restrict__ Wk,
                                             const float* __restrict__ Wv,
                                             unsigned short* __restrict__ Wt) {
    int idx = blockIdx.x * 256 + threadIdx.x;          // 3*64*384 = 73728
    if (idx >= 3 * 64 * 384) return;
    int w   = idx / (64 * 384);
    int rem = idx % (64 * 384);
    int n = rem / 384, k = rem % 384;
    const float* W = (w == 0) ? Wq : ((w == 1) ? Wk : Wv);
    Wt[idx] = f2bf(W[k * 64 + n]);
}

// ---------------- kernel 1: qkv = x @ [Wq|Wk|Wv] ----------------
// Tile 128x192, 256 threads (4 waves 2x2, wave tile 64x96), K-step 64, 6 steps.
// A: fp32 global -> reg (prefetched one step ahead; survives barriers because we
//    use raw s_barrier + counted vmcnt, not __syncthreads) -> cvt bf16 -> LDS (pad 72).
// B: global_load_lds 16B direct to LDS, chunk-XOR swizzled on the SOURCE side
//    (linear dest), read back with the same XOR -> conflict-free ds_read_b128.
__global__ __launch_bounds__(256, 2) void qkv_gemm(const float* __restrict__ x,
                                                   const unsigned short* __restrict__ Wt,
                                                   unsigned short* __restrict__ q_ws,
                                                   unsigned short* __restrict__ k_ws,
                                                   unsigned short* __restrict__ vt_ws) {
    __shared__ __align__(16) unsigned short A_lds[128 * 72];   // [row][k], stride 72 (2-way free)
    __shared__ __align__(16) unsigned short B_lds[192 * 64];   // [col][k], linear, content swizzled

    const int tid  = threadIdx.x;
    const int lane = tid & 63;
    const int wid  = tid >> 6;
    const int wr = wid >> 1, wc = wid & 1;
    const int l15 = lane & 15, lg = lane >> 4;
    const int row0 = blockIdx.x * 128;

    // B glds addressing: chunk c = wid*6+i covers cols c*8..c*8+7, full 64-k slab.
    // lane l -> col = c*8 + (l>>3), phys k-chunk = l&7, logical k-chunk = (l&7)^(l>>3).
    const int gcol_off = lane >> 3;                       // 0..7
    const int gkc      = ((lane & 7) ^ (lane >> 3)) * 8;  // pre-swizzled source k offset

    float4 aR[8];
    // ---- prologue: issue A(0) then B(0) ----
#pragma unroll
    for (int i = 0; i < 8; ++i) {
        int f = tid + 256 * i;                            // float4 id in 128x64 tile
        aR[i] = *reinterpret_cast<const float4*>(x + (size_t)(row0 + (f >> 4)) * 384 + (f & 15) * 4);
    }
    __builtin_amdgcn_sched_barrier(0);
#pragma unroll
    for (int i = 0; i < 6; ++i) {
        int c = wid * 6 + i;
        GLDS16(Wt + (size_t)(c * 8 + gcol_off) * 384 + gkc, &B_lds[c * 512]);
    }
    __builtin_amdgcn_sched_barrier(0);
    asm volatile("s_waitcnt vmcnt(6)" ::: "memory");      // A(0) regs ready; 6 glds in flight
#pragma unroll
    for (int i = 0; i < 8; ++i) {
        int f = tid + 256 * i;
        ushort4 h;
        h.x = f2bf(aR[i].x); h.y = f2bf(aR[i].y); h.z = f2bf(aR[i].z); h.w = f2bf(aR[i].w);
        *reinterpret_cast<ushort4*>(&A_lds[(f >> 4) * 72 + (f & 15) * 4]) = h;
    }
#pragma unroll
    for (int i = 0; i < 8; ++i) {                         // prefetch A(1)
        int f = tid + 256 * i;
        aR[i] = *reinterpret_cast<const float4*>(x + (size_t)(row0 + (f >> 4)) * 384 + 64 + (f & 15) * 4);
    }
    __builtin_amdgcn_sched_barrier(0);
    asm volatile("s_waitcnt lgkmcnt(0)" ::: "memory");    // A writes done
    asm volatile("s_waitcnt vmcnt(8)" ::: "memory");      // glds B(0) landed; A(1) in flight
    __builtin_amdgcn_s_barrier();

    f32x4 acc[4][6] = {};

#pragma unroll
    for (int s = 0; s < 6; ++s) {
        // ---- compute step s ----
#pragma unroll
        for (int kk = 0; kk < 2; ++kk) {
            bf16x8 a[4], b[6];
#pragma unroll
            for (int m = 0; m < 4; ++m)
                a[m] = *reinterpret_cast<const bf16x8*>(&A_lds[(wr * 64 + m * 16 + l15) * 72 + kk * 32 + lg * 8]);
#pragma unroll
            for (int n = 0; n < 6; ++n) {
                int col = wc * 96 + n * 16 + l15;
                int byte = col * 128 + (((kk * 4 + lg) ^ (l15 & 7)) << 4);
                b[n] = *reinterpret_cast<const bf16x8*>(reinterpret_cast<const char*>(B_lds) + byte);
            }
#pragma unroll
            for (int m = 0; m < 4; ++m)
#pragma unroll
                for (int n = 0; n < 6; ++n)
                    acc[m][n] = __builtin_amdgcn_mfma_f32_16x16x32_bf16(a[m], b[n], acc[m][n], 0, 0, 0);
        }
        if (s < 5) {
            __builtin_amdgcn_s_barrier();                 // B1: all waves done reading step s
            const int k1 = (s + 1) * 64;
#pragma unroll
            for (int i = 0; i < 6; ++i) {                 // issue glds B(s+1)
                int c = wid * 6 + i;
                GLDS16(Wt + (size_t)(c * 8 + gcol_off) * 384 + k1 + gkc, &B_lds[c * 512]);
            }
            __builtin_amdgcn_sched_barrier(0);
            asm volatile("s_waitcnt vmcnt(6)" ::: "memory");   // A(s+1) regs ready
#pragma unroll
            for (int i = 0; i < 8; ++i) {                 // cvt + write A(s+1)
                int f = tid + 256 * i;
                ushort4 h;
                h.x = f2bf(aR[i].x); h.y = f2bf(aR[i].y); h.z = f2bf(aR[i].z); h.w = f2bf(aR[i].w);
                *reinterpret_cast<ushort4*>(&A_lds[(f >> 4) * 72 + (f & 15) * 4]) = h;
            }
            if (s < 4) {
#pragma unroll
                for (int i = 0; i < 8; ++i) {             // prefetch A(s+2)
                    int f = tid + 256 * i;
                    aR[i] = *reinterpret_cast<const float4*>(x + (size_t)(row0 + (f >> 4)) * 384 + (s + 2) * 64 + (f & 15) * 4);
                }
            }
            __builtin_amdgcn_sched_barrier(0);
            asm volatile("s_waitcnt lgkmcnt(0)" ::: "memory");
            if (s < 4) { asm volatile("s_waitcnt vmcnt(8)" ::: "memory"); }
            else       { asm volatile("s_waitcnt vmcnt(0)" ::: "memory"); }
            __builtin_amdgcn_s_barrier();                 // B2: stage of s+1 visible
        }
    }

    // ---- epilogue: C/D layout col=lane&15, row=(lane>>4)*4+j ----
#pragma unroll
    for (int m = 0; m < 4; ++m) {
#pragma unroll
        for (int n = 0; n < 6; ++n) {
            int colb = wc * 96 + n * 16 + l15;
#pragma unroll
            for (int j = 0; j < 4; ++j) {
                int row = row0 + wr * 64 + m * 16 + lg * 4 + j;
                unsigned short hv = f2bf(acc[m][n][j]);
                if (colb < 64) {
                    q_ws[(size_t)row * 64 + colb] = hv;
                } else if (colb < 128) {
                    k_ws[(size_t)row * 64 + (colb - 64)] = hv;
                } else {
                    int bb = row >> 8, t = row & 255, h = colb - 128;
                    vt_ws[((size_t)bb * 64 + h) * 256 + t] = hv;   // v stored transposed
                }
            }
        }
    }
}

// ---------------- kernel 2: causal flash attention, one block per batch ----------------
__global__ __launch_bounds__(256, 1) void attn(const unsigned short* __restrict__ q_ws,
                                               const unsigned short* __restrict__ k_ws,
                                               const unsigned short* __restrict__ vt_ws,
                                               float* __restrict__ out) {
    __shared__ unsigned short P_lds[4][64][72];   // per-wave P staging, padded

    const int b = blockIdx.x;
    const int tid = threadIdx.x, lane = tid & 63, w = tid >> 6;
    const int l15 = lane & 15, lg = lane >> 4;
    const unsigned short* qb = q_ws + (size_t)b * 256 * 64;
    const unsigned short* kb = k_ws + (size_t)b * 256 * 64;
    const unsigned short* vb = vt_ws + (size_t)b * 64 * 256;
    float* ob = out + (size_t)b * 256 * 64;
    const int r0 = w * 64;
    const float scale = 0.05103103630798287f;     // 384^-0.5

    f32x4 o[4][4] = {};
    float M[4][4], L[4][4];
#pragma unroll
    for (int m = 0; m < 4; ++m)
#pragma unroll
        for (int j = 0; j < 4; ++j) { M[m][j] = -1e30f; L[m][j] = 0.f; }

    for (int jt = 0; jt <= w; ++jt) {
        // ---- S = q @ K^T for this 64-col tile ----
        f32x4 s[4][4] = {};
#pragma unroll
        for (int kk = 0; kk < 2; ++kk) {
            bf16x8 aq[4], bk[4];
#pragma unroll
            for (int m = 0; m < 4; ++m)
                aq[m] = *reinterpret_cast<const bf16x8*>(qb + (size_t)(r0 + m * 16 + l15) * 64 + kk * 32 + lg * 8);
#pragma unroll
            for (int n = 0; n < 4; ++n)
                bk[n] = *reinterpret_cast<const bf16x8*>(kb + (size_t)(jt * 64 + n * 16 + l15) * 64 + kk * 32 + lg * 8);
#pragma unroll
            for (int m = 0; m < 4; ++m)
#pragma unroll
                for (int n = 0; n < 4; ++n)
                    s[m][n] = __builtin_amdgcn_mfma_f32_16x16x32_bf16(aq[m], bk[n], s[m][n], 0, 0, 0);
        }
        // ---- scale + causal mask + tile row-max ----
        float tm[4][4];
#pragma unroll
        for (int m = 0; m < 4; ++m)
#pragma unroll
            for (int j = 0; j < 4; ++j) tm[m][j] = -1e30f;
#pragma unroll
        for (int m = 0; m < 4; ++m) {
#pragma unroll
            for (int n = 0; n < 4; ++n) {
                int colg = jt * 64 + n * 16 + l15;
#pragma unroll
                for (int j = 0; j < 4; ++j) {
                    int rowg = r0 + m * 16 + lg * 4 + j;
                    float v = s[m][n][j] * scale;
                    if (colg > rowg) v = -1e30f;
                    s[m][n][j] = v;
                    tm[m][j] = fmaxf(tm[m][j], v);
                }
            }
        }
#pragma unroll
        for (int m = 0; m < 4; ++m)
#pragma unroll
            for (int j = 0; j < 4; ++j) {
                float v = tm[m][j];
                v = fmaxf(v, __shfl_xor(v, 1));
                v = fmaxf(v, __shfl_xor(v, 2));
                v = fmaxf(v, __shfl_xor(v, 4));
                v = fmaxf(v, __shfl_xor(v, 8));
                tm[m][j] = v;
            }
        float alpha[4][4];
#pragma unroll
        for (int m = 0; m < 4; ++m)
#pragma unroll
            for (int j = 0; j < 4; ++j) {
                float mn = fmaxf(M[m][j], tm[m][j]);
                alpha[m][j] = __expf(M[m][j] - mn);
                M[m][j] = mn;
            }
        // ---- P = exp(S - M), tile row-sum ----
        float ts[4][4] = {};
#pragma unroll
        for (int m = 0; m < 4; ++m)
#pragma unroll
            for (int n = 0; n < 4; ++n)
#pragma unroll
                for (int j = 0; j < 4; ++j) {
                    float p = __expf(s[m][n][j] - M[m][j]);
                    s[m][n][j] = p;
                    ts[m][j] += p;
                }
#pragma unroll
        for (int m = 0; m < 4; ++m)
#pragma unroll
            for (int j = 0; j < 4; ++j) {
                float v = ts[m][j];
                v += __shfl_xor(v, 1);
                v += __shfl_xor(v, 2);
                v += __shfl_xor(v, 4);
                v += __shfl_xor(v, 8);
                L[m][j] = L[m][j] * alpha[m][j] + v;
            }
        // ---- rescale O ----
#pragma unroll
        for (int m = 0; m < 4; ++m)
#pragma unroll
            for (int n = 0; n < 4; ++n)
#pragma unroll
                for (int j = 0; j < 4; ++j) o[m][n][j] *= alpha[m][j];
        // ---- P -> LDS (bf16) for A-operand restage ----
#pragma unroll
        for (int m = 0; m < 4; ++m)
#pragma unroll
            for (int n = 0; n < 4; ++n)
#pragma unroll
                for (int j = 0; j < 4; ++j)
                    P_lds[w][m * 16 + lg * 4 + j][n * 16 + l15] = f2bf(s[m][n][j]);
        asm volatile("s_waitcnt lgkmcnt(0)" ::: "memory");   // wave-internal LDS RAW fence
        // ---- O += P @ V  (V transposed in global: vb[h][t]) ----
#pragma unroll
        for (int kk = 0; kk < 2; ++kk) {
            bf16x8 ap[4], bv[4];
#pragma unroll
            for (int m = 0; m < 4; ++m)
                ap[m] = *reinterpret_cast<const bf16x8*>(&P_lds[w][m * 16 + l15][kk * 32 + lg * 8]);
#pragma unroll
            for (int n = 0; n < 4; ++n)
                bv[n] = *reinterpret_cast<const bf16x8*>(vb + (size_t)(n * 16 + l15) * 256 + jt * 64 + kk * 32 + lg * 8);
#pragma unroll
            for (int m = 0; m < 4; ++m)
#pragma unroll
                for (int n = 0; n < 4; ++n)
                    o[m][n] = __builtin_amdgcn_mfma_f32_16x16x32_bf16(ap[m], bv[n], o[m][n], 0, 0, 0);
        }
    }
    // ---- normalize + store fp32 ----
#pragma unroll
    for (int m = 0; m < 4; ++m) {
#pragma unroll
        for (int n = 0; n < 4; ++n) {
            int h = n * 16 + l15;
#pragma unroll
            for (int j = 0; j < 4; ++j) {
                int t = r0 + m * 16 + lg * 4 + j;
                ob[(size_t)t * 64 + h] = o[m][n][j] / L[m][j];
            }
        }
    }
}

extern "C" void kernel_launch(void* const* d_in, const int* in_sizes, int n_in,
                              void* d_out, int out_size, void* d_ws, size_t ws_size,
                              hipStream_t stream) {
    const float* x  = (const float*)d_in[0];
    const float* Wq = (const float*)d_in[1];
    const float* Wk = (const float*)d_in[2];
    const float* Wv = (const float*)d_in[3];
    float* out = (float*)d_out;

    char* ws = (char*)d_ws;
    unsigned short* q_ws  = (unsigned short*)(ws);                 // [65536][64] bf16
    unsigned short* k_ws  = (unsigned short*)(ws + 8388608);       // [65536][64] bf16
    unsigned short* vt_ws = (unsigned short*)(ws + 16777216);      // [256][64][256] bf16 (v^T)
    unsigned short* Wt    = (unsigned short*)(ws + 25165824);      // [192][384] bf16

    wprep<<<288, 256, 0, stream>>>(Wq, Wk, Wv, Wt);
    qkv_gemm<<<512, 256, 0, stream>>>(x, Wt, q_ws, k_ws, vt_ws);
    attn<<<256, 256, 0, stream>>>(q_ws, k_ws, vt_ws, out);
}